// Round 1
// baseline (670.463 us; speedup 1.0000x reference)
//
#include <hip/hip_runtime.h>
#include <hip/hip_bf16.h>

#define BB 4096
#define DD 1024
#define NBF 16
#define HH 2048
#define KK 16384   // DD*NBF
#define LN_EPS 1e-5f

typedef short bs8 __attribute__((ext_vector_type(8)));   // 8 bf16 in 4 VGPRs (MFMA A/B frag)
typedef float f32x4 __attribute__((ext_vector_type(4))); // MFMA C/D frag

__device__ __forceinline__ unsigned short f2bf(float f) {
  union { float f; unsigned int u; } c; c.f = f;
  unsigned int u = c.u;
  return (unsigned short)((u + 0x7FFFu + ((u >> 16) & 1u)) >> 16);  // RNE
}

__device__ __forceinline__ float softplusf(float x) {
  return (x > 20.f) ? x : log1pf(expf(x));
}

// cs[d*16+k] = centers[d][k] / (softplus(width[d]) + 1e-6)
__global__ void prep_kernel(const float* __restrict__ centers, const float* __restrict__ width,
                            float* __restrict__ cs) {
  const int i = blockIdx.x * 256 + threadIdx.x;  // 16384 total
  const int d = i >> 4;
  const float w = softplusf(width[d]) + 1e-6f;
  cs[i] = centers[i] / w;
}

// LayerNorm -> xs = x_n / w  (fp32), and y_lin[b] = dot(x_n, sh_w) + sh_b
__global__ __launch_bounds__(256)
void ln_kernel(const float* __restrict__ x, const float* __restrict__ g,
               const float* __restrict__ be, const float* __restrict__ width,
               const float* __restrict__ sh_w, const float* __restrict__ sh_b,
               float* __restrict__ xs, float* __restrict__ ylin) {
  __shared__ float red[8];
  const int b = blockIdx.x, tid = threadIdx.x;
  const float4 v = ((const float4*)(x + (size_t)b * DD))[tid];
  float s  = v.x + v.y + v.z + v.w;
  float ss = v.x*v.x + v.y*v.y + v.z*v.z + v.w*v.w;
  #pragma unroll
  for (int off = 32; off > 0; off >>= 1) {
    s  += __shfl_xor(s, off);
    ss += __shfl_xor(ss, off);
  }
  if ((tid & 63) == 0) { red[(tid>>6)*2] = s; red[(tid>>6)*2+1] = ss; }
  __syncthreads();
  const float sum   = red[0]+red[2]+red[4]+red[6];
  const float sumsq = red[1]+red[3]+red[5]+red[7];
  const float mu   = sum * (1.f/DD);
  const float var  = sumsq * (1.f/DD) - mu*mu;
  const float rstd = rsqrtf(var + LN_EPS);
  const float4 g4 = ((const float4*)g)[tid];
  const float4 b4 = ((const float4*)be)[tid];
  const float4 w4 = ((const float4*)width)[tid];
  const float4 s4 = ((const float4*)sh_w)[tid];
  const float xn0 = (v.x - mu)*rstd*g4.x + b4.x;
  const float xn1 = (v.y - mu)*rstd*g4.y + b4.y;
  const float xn2 = (v.z - mu)*rstd*g4.z + b4.z;
  const float xn3 = (v.w - mu)*rstd*g4.w + b4.w;
  float4 o;
  o.x = xn0 / (softplusf(w4.x) + 1e-6f);
  o.y = xn1 / (softplusf(w4.y) + 1e-6f);
  o.z = xn2 / (softplusf(w4.z) + 1e-6f);
  o.w = xn3 / (softplusf(w4.w) + 1e-6f);
  ((float4*)(xs + (size_t)b * DD))[tid] = o;
  float yd = xn0*s4.x + xn1*s4.y + xn2*s4.z + xn3*s4.w;
  #pragma unroll
  for (int off = 32; off > 0; off >>= 1) yd += __shfl_xor(yd, off);
  __syncthreads();                 // red[] reuse: everyone done reading above
  if ((tid & 63) == 0) red[tid>>6] = yd;
  __syncthreads();
  if (tid == 0) ylin[b] = red[0]+red[1]+red[2]+red[3] + sh_b[0];
}

// fc1_w fp32 -> bf16
__global__ void cvt_kernel(const float* __restrict__ w, unsigned short* __restrict__ wb) {
  const int n4 = HH * KK / 4;
  const int stride = gridDim.x * blockDim.x;
  for (int i = blockIdx.x * blockDim.x + threadIdx.x; i < n4; i += stride) {
    const float4 v = ((const float4*)w)[i];
    ushort4 o;
    o.x = f2bf(v.x); o.y = f2bf(v.y); o.z = f2bf(v.z); o.w = f2bf(v.w);
    ((ushort4*)wb)[i] = o;
  }
}

// h = gelu( z @ fc1_w^T + fc1_b ),  z computed on the fly from xs/cs.
// 128x128 tile, BK=64, 4 waves each 64x64. A: reg-compute + XOR-swizzled ds_write.
// B: global_load_lds width=16 (linear).
__global__ __launch_bounds__(256, 2)
void gemm_kernel(const float* __restrict__ xs, const float* __restrict__ cs,
                 const unsigned short* __restrict__ wb, const float* __restrict__ fc1_b,
                 float* __restrict__ h) {
  __shared__ unsigned short As[128 * 64];
  __shared__ unsigned short Bs[128 * 64];
  const int tid  = threadIdx.x;
  const int lane = tid & 63;
  const int wv   = tid >> 6;
  const int bid  = blockIdx.x;
  const int bm = bid & 31;     // M/128 = 32  (fastest -> consecutive blocks share B panel)
  const int bn = bid >> 5;     // N/128 = 16
  const int wr = wv >> 1, wc = wv & 1;

  f32x4 acc[4][4];
  #pragma unroll
  for (int m = 0; m < 4; ++m)
    #pragma unroll
    for (int n = 0; n < 4; ++n)
      acc[m][n] = (f32x4){0.f, 0.f, 0.f, 0.f};

  const int arow  = tid >> 1;        // 0..127
  const int ahalf = tid & 1;         // which 32-col half
  const float* xs_row = xs + (size_t)(bm * 128 + arow) * DD;

  const int bcol = (lane & 7) * 8;   // elem offset within B row for staging
  const int frow = lane & 15;
  const int fk   = (lane >> 4) * 8;
  const int fkb  = (lane >> 4);      // 16B-block index 0..3

  for (int t = 0; t < KK / 64; ++t) {
    const int k0 = t * 64;
    __syncthreads();   // previous tile fully consumed
    // ---- stage B: 4 x global_load_lds (wave-uniform LDS base + lane*16) ----
    #pragma unroll
    for (int i = 0; i < 4; ++i) {
      const int r = i * 32 + wv * 8 + (lane >> 3);
      const unsigned short* gp = wb + (size_t)(bn * 128 + r) * KK + (k0 + bcol);
      unsigned short* lp = &Bs[(i * 32 + wv * 8) * 64];
      __builtin_amdgcn_global_load_lds(
          (const __attribute__((address_space(1))) void*)gp,
          (__attribute__((address_space(3))) void*)lp, 16, 0, 0);
    }
    // ---- compute A tile: phi = relu(1 - |xs - cs|), 32 elems/thread ----
    const int d0 = (k0 >> 4) + ahalf * 2;
    const float xv0 = xs_row[d0];
    const float xv1 = xs_row[d0 + 1];
    const float4* cs4 = (const float4*)(cs + k0 + ahalf * 32);
    unsigned short av[32];
    #pragma unroll
    for (int q = 0; q < 8; ++q) {
      const float4 c4 = cs4[q];
      const float xv = (q < 4) ? xv0 : xv1;
      av[q*4+0] = f2bf(fmaxf(0.f, 1.f - fabsf(xv - c4.x)));
      av[q*4+1] = f2bf(fmaxf(0.f, 1.f - fabsf(xv - c4.y)));
      av[q*4+2] = f2bf(fmaxf(0.f, 1.f - fabsf(xv - c4.z)));
      av[q*4+3] = f2bf(fmaxf(0.f, 1.f - fabsf(xv - c4.w)));
    }
    // ---- ds_write A, XOR-swizzled 16B blocks (kills 32-way write conflict) ----
    #pragma unroll
    for (int qb = 0; qb < 4; ++qb) {
      bs8 vv;
      #pragma unroll
      for (int j = 0; j < 8; ++j) vv[j] = (short)av[qb*8 + j];
      const int kb  = ahalf * 4 + qb;
      const int pos = kb ^ (arow & 7);
      *reinterpret_cast<bs8*>(&As[arow * 64 + pos * 8]) = vv;
    }
    __syncthreads();   // A+B staged (compiler drains vmcnt+lgkmcnt here)
    // ---- MFMA ----
    #pragma unroll
    for (int ks = 0; ks < 2; ++ks) {
      bs8 af[4], bfr[4];
      #pragma unroll
      for (int m = 0; m < 4; ++m) {
        const int Ra = wr * 64 + m * 16 + frow;
        const int kb = ks * 4 + fkb;
        af[m] = *reinterpret_cast<const bs8*>(&As[Ra * 64 + ((kb ^ (Ra & 7)) * 8)]);
      }
      #pragma unroll
      for (int n = 0; n < 4; ++n) {
        const int Rb = wc * 64 + n * 16 + frow;
        bfr[n] = *reinterpret_cast<const bs8*>(&Bs[Rb * 64 + ks * 32 + fk]);
      }
      #pragma unroll
      for (int m = 0; m < 4; ++m)
        #pragma unroll
        for (int n = 0; n < 4; ++n)
          acc[m][n] = __builtin_amdgcn_mfma_f32_16x16x32_bf16(af[m], bfr[n], acc[m][n], 0, 0, 0);
    }
  }
  // ---- epilogue: h = gelu(acc + fc1_b)  (C/D: col=lane&15, row=(lane>>4)*4+reg) ----
  const int row0 = bm * 128 + wr * 64;
  const int col0 = bn * 128 + wc * 64;
  #pragma unroll
  for (int n = 0; n < 4; ++n) {
    const int col = col0 + n * 16 + frow;
    const float bias = fc1_b[col];
    #pragma unroll
    for (int m = 0; m < 4; ++m) {
      #pragma unroll
      for (int r = 0; r < 4; ++r) {
        const int row = row0 + m * 16 + (lane >> 4) * 4 + r;
        const float xg = acc[m][n][r] + bias;
        h[(size_t)row * HH + col] = 0.5f * xg * (1.f + erff(xg * 0.70710678118f));
      }
    }
  }
}

// out[b] = dot(h[b], hm_w) + hm_b + relu(gamma)*y_lin[b];  out[BB+b] = dot(h[b], hv_w) + hv_b
__global__ __launch_bounds__(256)
void head_kernel(const float* __restrict__ h, const float* __restrict__ hm_w,
                 const float* __restrict__ hm_b, const float* __restrict__ hv_w,
                 const float* __restrict__ hv_b, const float* __restrict__ ylin,
                 const float* __restrict__ gamma, float* __restrict__ out) {
  __shared__ float red[8];
  const int b = blockIdx.x, tid = threadIdx.x;
  const float4* hr  = (const float4*)(h + (size_t)b * HH);
  const float4* wm  = (const float4*)hm_w;
  const float4* wvv = (const float4*)hv_w;
  float dm = 0.f, dv = 0.f;
  #pragma unroll
  for (int i = 0; i < 2; ++i) {
    const int c = tid + i * 256;
    const float4 hv4 = hr[c];
    const float4 m4  = wm[c];
    const float4 v4  = wvv[c];
    dm += hv4.x*m4.x + hv4.y*m4.y + hv4.z*m4.z + hv4.w*m4.w;
    dv += hv4.x*v4.x + hv4.y*v4.y + hv4.z*v4.z + hv4.w*v4.w;
  }
  #pragma unroll
  for (int off = 32; off > 0; off >>= 1) {
    dm += __shfl_xor(dm, off);
    dv += __shfl_xor(dv, off);
  }
  if ((tid & 63) == 0) { red[(tid>>6)*2] = dm; red[(tid>>6)*2+1] = dv; }
  __syncthreads();
  if (tid == 0) {
    const float sm = red[0]+red[2]+red[4]+red[6] + hm_b[0];
    const float sv = red[1]+red[3]+red[5]+red[7] + hv_b[0];
    out[b]      = sm + fmaxf(gamma[0], 0.f) * ylin[b];
    out[BB + b] = sv;
  }
}

extern "C" void kernel_launch(void* const* d_in, const int* in_sizes, int n_in,
                              void* d_out, int out_size, void* d_ws, size_t ws_size,
                              hipStream_t stream) {
  const float* x       = (const float*)d_in[0];
  const float* ln_g    = (const float*)d_in[1];
  const float* ln_b    = (const float*)d_in[2];
  const float* centers = (const float*)d_in[3];
  const float* width   = (const float*)d_in[4];
  const float* fc1_w   = (const float*)d_in[5];
  const float* fc1_b   = (const float*)d_in[6];
  const float* hm_w    = (const float*)d_in[7];
  const float* hm_b    = (const float*)d_in[8];
  const float* hv_w    = (const float*)d_in[9];
  const float* hv_b    = (const float*)d_in[10];
  const float* sh_w    = (const float*)d_in[11];
  const float* sh_b    = (const float*)d_in[12];
  const float* gamma   = (const float*)d_in[13];

  char* ws = (char*)d_ws;
  // ws layout: cs 256KB | ylin 256KB | xs 16MB | wb(bf16) 64MB | h 32MB  (~118MB total)
  float* cs            = (float*)(ws);
  float* ylin          = (float*)(ws + (256 << 10));
  float* xs            = (float*)(ws + (512 << 10));
  unsigned short* wb   = (unsigned short*)(ws + (512 << 10) + (16 << 20));
  float* h             = (float*)(ws + (512 << 10) + (16 << 20) + (64 << 20));
  float* out           = (float*)d_out;

  prep_kernel<<<dim3(64),   dim3(256), 0, stream>>>(centers, width, cs);
  ln_kernel  <<<dim3(4096), dim3(256), 0, stream>>>(x, ln_g, ln_b, width, sh_w, sh_b, xs, ylin);
  cvt_kernel <<<dim3(4096), dim3(256), 0, stream>>>(fc1_w, wb);
  gemm_kernel<<<dim3(512),  dim3(256), 0, stream>>>(xs, cs, wb, fc1_b, h);
  head_kernel<<<dim3(4096), dim3(256), 0, stream>>>(h, hm_w, hm_b, hv_w, hv_b, ylin, gamma, out);
}

// Round 2
// 427.339 us; speedup vs baseline: 1.5689x; 1.5689x over previous
//
#include <hip/hip_runtime.h>
#include <hip/hip_bf16.h>

#define BB 4096
#define DD 1024
#define NBF 16
#define HH 2048
#define KK 16384   // DD*NBF
#define LN_EPS 1e-5f

typedef short bs8 __attribute__((ext_vector_type(8)));            // 8 bf16 (MFMA A/B frag)
typedef unsigned short us8 __attribute__((ext_vector_type(8)));   // 8 bf16 store
typedef float f32x4 __attribute__((ext_vector_type(4)));          // MFMA C/D frag

__device__ __forceinline__ unsigned short f2bf(float f) {
  union { float f; unsigned int u; } c; c.f = f;
  unsigned int u = c.u;
  return (unsigned short)((u + 0x7FFFu + ((u >> 16) & 1u)) >> 16);  // RNE
}
__device__ __forceinline__ float bf2f(unsigned short s) {
  union { unsigned int u; float f; } c; c.u = ((unsigned int)s) << 16;
  return c.f;
}
__device__ __forceinline__ float softplusf(float x) {
  return (x > 20.f) ? x : log1pf(expf(x));
}

// cs[d*16+k] = centers[d][k] / (softplus(width[d]) + 1e-6)
__global__ void prep_kernel(const float* __restrict__ centers, const float* __restrict__ width,
                            float* __restrict__ cs) {
  const int i = blockIdx.x * 256 + threadIdx.x;  // 16384 total
  const int d = i >> 4;
  const float w = softplusf(width[d]) + 1e-6f;
  cs[i] = centers[i] / w;
}

// LayerNorm + triangular-basis expansion -> z (bf16 [B,KK]), and ylin[b]
__global__ __launch_bounds__(256)
void zexp_kernel(const float* __restrict__ x, const float* __restrict__ g,
                 const float* __restrict__ be, const float* __restrict__ width,
                 const float* __restrict__ sh_w, const float* __restrict__ sh_b,
                 const float* __restrict__ cs,
                 unsigned short* __restrict__ z, float* __restrict__ ylin) {
  __shared__ float red[8];
  const int b = blockIdx.x, tid = threadIdx.x;
  const float4 v = ((const float4*)(x + (size_t)b * DD))[tid];
  float s  = v.x + v.y + v.z + v.w;
  float ss = v.x*v.x + v.y*v.y + v.z*v.z + v.w*v.w;
  #pragma unroll
  for (int off = 32; off > 0; off >>= 1) {
    s  += __shfl_xor(s, off);
    ss += __shfl_xor(ss, off);
  }
  if ((tid & 63) == 0) { red[(tid>>6)*2] = s; red[(tid>>6)*2+1] = ss; }
  __syncthreads();
  const float sum   = red[0]+red[2]+red[4]+red[6];
  const float sumsq = red[1]+red[3]+red[5]+red[7];
  const float mu   = sum * (1.f/DD);
  const float var  = sumsq * (1.f/DD) - mu*mu;
  const float rstd = rsqrtf(var + LN_EPS);
  const float4 g4 = ((const float4*)g)[tid];
  const float4 b4 = ((const float4*)be)[tid];
  const float4 w4 = ((const float4*)width)[tid];
  const float4 s4 = ((const float4*)sh_w)[tid];
  const float xn0 = (v.x - mu)*rstd*g4.x + b4.x;
  const float xn1 = (v.y - mu)*rstd*g4.y + b4.y;
  const float xn2 = (v.z - mu)*rstd*g4.z + b4.z;
  const float xn3 = (v.w - mu)*rstd*g4.w + b4.w;
  float xsv[4];
  xsv[0] = xn0 / (softplusf(w4.x) + 1e-6f);
  xsv[1] = xn1 / (softplusf(w4.y) + 1e-6f);
  xsv[2] = xn2 / (softplusf(w4.z) + 1e-6f);
  xsv[3] = xn3 / (softplusf(w4.w) + 1e-6f);
  // expansion: this thread owns d = tid*4..tid*4+3 -> 64 contiguous bf16
  unsigned short* zr = z + (size_t)b * KK + tid * 64;
  #pragma unroll
  for (int j = 0; j < 4; ++j) {
    const float4* c4 = (const float4*)(cs + (tid * 4 + j) * 16);
    const float xv = xsv[j];
    us8 o0, o1;
    #pragma unroll
    for (int q = 0; q < 2; ++q) {
      const float4 ca = c4[q*2], cb = c4[q*2+1];
      us8& o = q ? o1 : o0;
      o[0] = f2bf(fmaxf(0.f, 1.f - fabsf(xv - ca.x)));
      o[1] = f2bf(fmaxf(0.f, 1.f - fabsf(xv - ca.y)));
      o[2] = f2bf(fmaxf(0.f, 1.f - fabsf(xv - ca.z)));
      o[3] = f2bf(fmaxf(0.f, 1.f - fabsf(xv - ca.w)));
      o[4] = f2bf(fmaxf(0.f, 1.f - fabsf(xv - cb.x)));
      o[5] = f2bf(fmaxf(0.f, 1.f - fabsf(xv - cb.y)));
      o[6] = f2bf(fmaxf(0.f, 1.f - fabsf(xv - cb.z)));
      o[7] = f2bf(fmaxf(0.f, 1.f - fabsf(xv - cb.w)));
    }
    ((us8*)(zr + j * 16))[0] = o0;
    ((us8*)(zr + j * 16))[1] = o1;
  }
  // y_lin
  float yd = xn0*s4.x + xn1*s4.y + xn2*s4.z + xn3*s4.w;
  #pragma unroll
  for (int off = 32; off > 0; off >>= 1) yd += __shfl_xor(yd, off);
  __syncthreads();
  if ((tid & 63) == 0) red[tid>>6] = yd;
  __syncthreads();
  if (tid == 0) ylin[b] = red[0]+red[1]+red[2]+red[3] + sh_b[0];
}

// fc1_w fp32 -> bf16
__global__ void cvt_kernel(const float* __restrict__ w, unsigned short* __restrict__ wb) {
  const int n4 = HH * KK / 4;
  const int stride = gridDim.x * blockDim.x;
  for (int i = blockIdx.x * blockDim.x + threadIdx.x; i < n4; i += stride) {
    const float4 v = ((const float4*)w)[i];
    ushort4 o;
    o.x = f2bf(v.x); o.y = f2bf(v.y); o.z = f2bf(v.z); o.w = f2bf(v.w);
    ((ushort4*)wb)[i] = o;
  }
}

// h = gelu( z @ wb^T + fc1_b ), bf16 out. 128x128 tile, BK=64, 4 waves of 64x64.
// Both operands: global_load_lds width=16, linear LDS dest, PRE-SWIZZLED global
// source (chunk ^= row&7) + matching XOR on ds_read (rule #21 both-sides).
__global__ __launch_bounds__(256, 2)
void gemm_kernel(const unsigned short* __restrict__ z, const unsigned short* __restrict__ wb,
                 const float* __restrict__ fc1_b, unsigned short* __restrict__ h) {
  __shared__ unsigned short As[128 * 64];
  __shared__ unsigned short Bs[128 * 64];
  const int tid  = threadIdx.x;
  const int lane = tid & 63;
  const int wv   = tid >> 6;
  // bijective XCD swizzle (512 % 8 == 0): each XCD gets a contiguous 64-block chunk
  const int bid = (blockIdx.x & 7) * 64 + (blockIdx.x >> 3);
  const int bm = bid & 31;     // M/128 = 32 (fastest -> consecutive blocks share B panel)
  const int bn = bid >> 5;     // N/128 = 16
  const int wr = wv >> 1, wc = wv & 1;

  f32x4 acc[4][4];
  #pragma unroll
  for (int m = 0; m < 4; ++m)
    #pragma unroll
    for (int n = 0; n < 4; ++n)
      acc[m][n] = (f32x4){0.f, 0.f, 0.f, 0.f};

  const int srow   = (lane >> 3);            // 0..7 row-in-8 group
  const int schunk = (lane & 7) ^ srow;      // pre-swizzled source 16B-chunk
  const int frow = lane & 15;
  const int fkb  = lane >> 4;                // 0..3

  const unsigned short* zbase  = z  + (size_t)(bm * 128) * KK;
  const unsigned short* wbbase = wb + (size_t)(bn * 128) * KK;

  for (int t = 0; t < KK / 64; ++t) {
    const int k0 = t * 64;
    __syncthreads();   // previous tile fully consumed
    #pragma unroll
    for (int i = 0; i < 4; ++i) {
      const int r = i * 32 + wv * 8 + srow;
      // A: z rows
      __builtin_amdgcn_global_load_lds(
          (const __attribute__((address_space(1))) void*)(zbase + (size_t)r * KK + k0 + schunk * 8),
          (__attribute__((address_space(3))) void*)(&As[(i * 32 + wv * 8) * 64]), 16, 0, 0);
      // B: wb rows
      __builtin_amdgcn_global_load_lds(
          (const __attribute__((address_space(1))) void*)(wbbase + (size_t)r * KK + k0 + schunk * 8),
          (__attribute__((address_space(3))) void*)(&Bs[(i * 32 + wv * 8) * 64]), 16, 0, 0);
    }
    __syncthreads();   // staged (compiler drains vmcnt here)
    #pragma unroll
    for (int ks = 0; ks < 2; ++ks) {
      const int kb = ks * 4 + fkb;
      bs8 af[4], bfr[4];
      #pragma unroll
      for (int m = 0; m < 4; ++m) {
        const int Ra = wr * 64 + m * 16 + frow;
        af[m] = *reinterpret_cast<const bs8*>(&As[Ra * 64 + ((kb ^ (Ra & 7)) * 8)]);
      }
      #pragma unroll
      for (int n = 0; n < 4; ++n) {
        const int Rb = wc * 64 + n * 16 + frow;
        bfr[n] = *reinterpret_cast<const bs8*>(&Bs[Rb * 64 + ((kb ^ (Rb & 7)) * 8)]);
      }
      #pragma unroll
      for (int m = 0; m < 4; ++m)
        #pragma unroll
        for (int n = 0; n < 4; ++n)
          acc[m][n] = __builtin_amdgcn_mfma_f32_16x16x32_bf16(af[m], bfr[n], acc[m][n], 0, 0, 0);
    }
  }
  // epilogue: h = gelu(acc + bias), bf16. C/D: col=lane&15, row=(lane>>4)*4+reg
  const int row0 = bm * 128 + wr * 64;
  const int col0 = bn * 128 + wc * 64;
  #pragma unroll
  for (int n = 0; n < 4; ++n) {
    const int col = col0 + n * 16 + frow;
    const float bias = fc1_b[col];
    #pragma unroll
    for (int m = 0; m < 4; ++m) {
      #pragma unroll
      for (int r = 0; r < 4; ++r) {
        const int row = row0 + m * 16 + fkb * 4 + r;
        const float xg = acc[m][n][r] + bias;
        h[(size_t)row * HH + col] = f2bf(0.5f * xg * (1.f + erff(xg * 0.70710678118f)));
      }
    }
  }
}

// out[b] = dot(h[b], hm_w) + hm_b + relu(gamma)*ylin[b];  out[BB+b] = dot(h[b], hv_w) + hv_b
__global__ __launch_bounds__(256)
void head_kernel(const unsigned short* __restrict__ h, const float* __restrict__ hm_w,
                 const float* __restrict__ hm_b, const float* __restrict__ hv_w,
                 const float* __restrict__ hv_b, const float* __restrict__ ylin,
                 const float* __restrict__ gamma, float* __restrict__ out) {
  __shared__ float red[8];
  const int b = blockIdx.x, tid = threadIdx.x;
  const us8 hv8 = ((const us8*)(h + (size_t)b * HH))[tid];
  const float4 m0 = ((const float4*)hm_w)[tid*2],  m1 = ((const float4*)hm_w)[tid*2+1];
  const float4 v0 = ((const float4*)hv_w)[tid*2],  v1 = ((const float4*)hv_w)[tid*2+1];
  float hf[8];
  #pragma unroll
  for (int i = 0; i < 8; ++i) hf[i] = bf2f((unsigned short)hv8[i]);
  float dm = hf[0]*m0.x + hf[1]*m0.y + hf[2]*m0.z + hf[3]*m0.w
           + hf[4]*m1.x + hf[5]*m1.y + hf[6]*m1.z + hf[7]*m1.w;
  float dv = hf[0]*v0.x + hf[1]*v0.y + hf[2]*v0.z + hf[3]*v0.w
           + hf[4]*v1.x + hf[5]*v1.y + hf[6]*v1.z + hf[7]*v1.w;
  #pragma unroll
  for (int off = 32; off > 0; off >>= 1) {
    dm += __shfl_xor(dm, off);
    dv += __shfl_xor(dv, off);
  }
  if ((tid & 63) == 0) { red[(tid>>6)*2] = dm; red[(tid>>6)*2+1] = dv; }
  __syncthreads();
  if (tid == 0) {
    const float sm = red[0]+red[2]+red[4]+red[6] + hm_b[0];
    const float sv = red[1]+red[3]+red[5]+red[7] + hv_b[0];
    out[b]      = sm + fmaxf(gamma[0], 0.f) * ylin[b];
    out[BB + b] = sv;
  }
}

extern "C" void kernel_launch(void* const* d_in, const int* in_sizes, int n_in,
                              void* d_out, int out_size, void* d_ws, size_t ws_size,
                              hipStream_t stream) {
  const float* x       = (const float*)d_in[0];
  const float* ln_g    = (const float*)d_in[1];
  const float* ln_b    = (const float*)d_in[2];
  const float* centers = (const float*)d_in[3];
  const float* width   = (const float*)d_in[4];
  const float* fc1_w   = (const float*)d_in[5];
  const float* fc1_b   = (const float*)d_in[6];
  const float* hm_w    = (const float*)d_in[7];
  const float* hm_b    = (const float*)d_in[8];
  const float* hv_w    = (const float*)d_in[9];
  const float* hv_b    = (const float*)d_in[10];
  const float* sh_w    = (const float*)d_in[11];
  const float* sh_b    = (const float*)d_in[12];
  const float* gamma   = (const float*)d_in[13];

  char* ws = (char*)d_ws;
  // ws layout: cs 64KB @0 | ylin 16KB @64KB | z 128MB @1MB | wb 64MB @129MB | h(bf16) 16MB @193MB
  float* cs            = (float*)(ws);
  float* ylin          = (float*)(ws + (64 << 10));
  unsigned short* z    = (unsigned short*)(ws + (1 << 20));
  unsigned short* wb   = (unsigned short*)(ws + (129ull << 20));
  unsigned short* h    = (unsigned short*)(ws + (193ull << 20));
  float* out           = (float*)d_out;

  prep_kernel<<<dim3(64),   dim3(256), 0, stream>>>(centers, width, cs);
  zexp_kernel<<<dim3(4096), dim3(256), 0, stream>>>(x, ln_g, ln_b, width, sh_w, sh_b, cs, z, ylin);
  cvt_kernel <<<dim3(4096), dim3(256), 0, stream>>>(fc1_w, wb);
  gemm_kernel<<<dim3(512),  dim3(256), 0, stream>>>(z, wb, fc1_b, h);
  head_kernel<<<dim3(4096), dim3(256), 0, stream>>>(h, hm_w, hm_b, hv_w, hv_b, ylin, gamma, out);
}